// Round 1
// baseline (241.838 us; speedup 1.0000x reference)
//
#include <hip/hip_runtime.h>
#include <hip/hip_bf16.h>

// Problem sizes (fixed by reference): B=2048, N=64, C=256, F=256
// out[b,n,f] = d[f,n]*h0[b,n,f] + sum_m off[f,n,m]*h1[b,m,f] + bias[f]
//   h0 = x@W[0], h1 = x@W[1], adj = softmax(mask ? e : NEG, axis=m),
//   d = diag(adj), off = adj w/ zeroed diag.

typedef __attribute__((ext_vector_type(8))) short  fragA;   // 8 bf16 = 4 VGPR
typedef __attribute__((ext_vector_type(4))) float  f32x4;
typedef __attribute__((ext_vector_type(8))) unsigned short u16x8;
typedef __attribute__((ext_vector_type(4))) unsigned short u16x4;

// workspace layout (bytes)
constexpr long OFF_OFF = 0;                          // bf16 off [256][64][64]  (2 MB)
constexpr long OFF_WT  = 2l * 1024 * 1024;           // bf16 Wt  flat [512][256] (256 KB)
constexpr long OFF_DS  = OFF_WT + 512l * 256 * 2;    // f32 dscale [64][256]    (64 KB)
constexpr long OFF_H1  = OFF_DS + 64l * 256 * 4;     // bf16 h1 [256][131072]   (64 MB)
constexpr long WS_NEED = OFF_H1 + 256l * 131072 * 2;

static __device__ inline unsigned short f2bf(float f) {
  __hip_bfloat16 h = __float2bfloat16(f);
  return __builtin_bit_cast(unsigned short, h);
}
static __device__ inline float bf2f(unsigned short u) {
  unsigned int x = ((unsigned int)u) << 16;
  return __builtin_bit_cast(float, x);
}

// ---------------------------------------------------------------- k_prep
// one wave per (f,n) row of e; block = 4 rows
__global__ __launch_bounds__(256) void k_prep(const float* __restrict__ e,
                                              const unsigned char* __restrict__ mask,
                                              char* __restrict__ ws_b) {
  unsigned short* off = (unsigned short*)(ws_b + OFF_OFF);
  float* dscale = (float*)(ws_b + OFF_DS);
  const int lane = threadIdx.x & 63;
  const int row  = blockIdx.x * 4 + (threadIdx.x >> 6);   // f*64 + n
  const int f = row >> 6, n = row & 63;

  // mask dtype sniff: self-loops guarantee diag true. If the buffer is u8,
  // all 64 diag bytes are nonzero; if it is i32, byte (n*65) is a middle
  // byte of a 0/1 int for any n%4!=0 and the test fails.
  bool is_u8 = __all(mask[lane * 65] != 0);
  bool mv;
  if (is_u8) mv = mask[n * 64 + lane] != 0;
  else       mv = ((const int*)mask)[n * 64 + lane] != 0;

  float v = mv ? e[(long)row * 64 + lane] : -1e30f;
  float mx = v;
#pragma unroll
  for (int s = 32; s; s >>= 1) mx = fmaxf(mx, __shfl_xor(mx, s));
  float ex = mv ? __expf(v - mx) : 0.f;
  float sm = ex;
#pragma unroll
  for (int s = 32; s; s >>= 1) sm += __shfl_xor(sm, s);
  float adj = ex / sm;
  if (lane == n) dscale[n * 256 + f] = adj;
  off[(long)row * 64 + lane] = f2bf(lane == n ? 0.f : adj);
}

// ---------------------------------------------------------------- k_wt
// W[2][C][F] f32 -> Wt bf16 flat [512(j=w*256+f)][256(c)]
__global__ __launch_bounds__(256) void k_wt(const float* __restrict__ W,
                                            char* __restrict__ ws_b) {
  unsigned short* Wt = (unsigned short*)(ws_b + OFF_WT);
  __shared__ float t[64][65];
  const int bid = blockIdx.x;           // 32 blocks: w(2) x f0(4) x c0(4)
  const int w = bid >> 4, f0 = ((bid >> 2) & 3) * 64, c0 = (bid & 3) * 64;
  const int tr = threadIdx.x >> 2, tc = (threadIdx.x & 3) * 16;
  const float* src = W + ((long)(w * 256 + c0 + tr)) * 256 + f0 + tc;
#pragma unroll
  for (int i = 0; i < 16; i += 4) {
    float4 v = *(const float4*)(src + i);
    t[tr][tc + i] = v.x; t[tr][tc + i + 1] = v.y;
    t[tr][tc + i + 2] = v.z; t[tr][tc + i + 3] = v.w;
  }
  __syncthreads();
  u16x8 p0, p1;
#pragma unroll
  for (int i = 0; i < 8; i++)  p0[i] = f2bf(t[tc + i][tr]);
#pragma unroll
  for (int i = 0; i < 8; i++)  p1[i] = f2bf(t[tc + 8 + i][tr]);
  unsigned short* dst = Wt + ((long)(w * 256 + f0 + tr)) * 256 + c0 + tc;
  *(u16x8*)dst = p0;
  *(u16x8*)(dst + 8) = p1;
}

// ---------------------------------------------------------------- k_gemm
// grid (2, 1024), block 512 (8 waves, 2x4 wave grid, wave tile 64x64)
// bcol==0: out = d*h0 + bias  (W0 cols);  bcol==1: h1 -> ws transposed bf16
__global__ __launch_bounds__(512) void k_gemm(const float* __restrict__ x,
                                              const float* __restrict__ bias,
                                              char* __restrict__ ws_b,
                                              float* __restrict__ out) {
  const unsigned short* Wt = (const unsigned short*)(ws_b + OFF_WT);
  const float* dscale = (const float*)(ws_b + OFF_DS);
  __shared__ __align__(16) unsigned short smem[256 * 136];   // 69632 B
  unsigned short* As = smem;               // [128][72]
  unsigned short* Bs = smem + 128 * 72;    // [256][72]

  const int tid  = threadIdx.x;
  const int bcol = blockIdx.x;                 // 0 -> h0 path, 1 -> h1 path
  const long R0  = (long)blockIdx.y * 128;     // row = b*64+n (or b*64+m)
  const int wid  = tid >> 6, lane = tid & 63;
  const int wr = wid & 1, wc = wid >> 1;       // 2 x 4 waves
  const int lr = lane & 15, lkb = (lane >> 4) * 8;

  f32x4 acc[4][4] = {};

  for (int k0 = 0; k0 < 256; k0 += 64) {
    { // stage A: x[R0..R0+127][k0..k0+63] f32 -> bf16, 16 el/thread
      int r = tid >> 2, cb = (tid & 3) * 16;
      const float* src = x + (R0 + r) * 256 + k0 + cb;
      float4 v0 = ((const float4*)src)[0];
      float4 v1 = ((const float4*)src)[1];
      float4 v2 = ((const float4*)src)[2];
      float4 v3 = ((const float4*)src)[3];
      u16x8 p0, p1;
      p0[0]=f2bf(v0.x); p0[1]=f2bf(v0.y); p0[2]=f2bf(v0.z); p0[3]=f2bf(v0.w);
      p0[4]=f2bf(v1.x); p0[5]=f2bf(v1.y); p0[6]=f2bf(v1.z); p0[7]=f2bf(v1.w);
      p1[0]=f2bf(v2.x); p1[1]=f2bf(v2.y); p1[2]=f2bf(v2.z); p1[3]=f2bf(v2.w);
      p1[4]=f2bf(v3.x); p1[5]=f2bf(v3.y); p1[6]=f2bf(v3.z); p1[7]=f2bf(v3.w);
      unsigned short* d = As + r * 72 + cb;
      *(u16x8*)d = p0;
      *(u16x8*)(d + 8) = p1;
    }
    { // stage B: Wt[bcol*256 + j][k0..k0+63], 32 el/thread
      int j = tid >> 1, cb = (tid & 1) * 32;
      const unsigned short* src = Wt + ((long)(bcol * 256 + j)) * 256 + k0 + cb;
      unsigned short* d = Bs + j * 72 + cb;
      *(u16x8*)(d)      = *(const u16x8*)(src);
      *(u16x8*)(d + 8)  = *(const u16x8*)(src + 8);
      *(u16x8*)(d + 16) = *(const u16x8*)(src + 16);
      *(u16x8*)(d + 24) = *(const u16x8*)(src + 24);
    }
    __syncthreads();
#pragma unroll
    for (int kk = 0; kk < 2; kk++) {
      fragA af[4], bfm[4];
#pragma unroll
      for (int i = 0; i < 4; i++)
        af[i] = *(const fragA*)(As + (wr * 64 + i * 16 + lr) * 72 + kk * 32 + lkb);
#pragma unroll
      for (int j = 0; j < 4; j++)
        bfm[j] = *(const fragA*)(Bs + (wc * 64 + j * 16 + lr) * 72 + kk * 32 + lkb);
#pragma unroll
      for (int i = 0; i < 4; i++)
#pragma unroll
        for (int j = 0; j < 4; j++)
          acc[i][j] = __builtin_amdgcn_mfma_f32_16x16x32_bf16(af[i], bfm[j], acc[i][j], 0, 0, 0);
    }
    __syncthreads();
  }

  if (bcol == 0) {
    // out = acc * d[n][f] + bias[f]
#pragma unroll
    for (int i = 0; i < 4; i++) {
#pragma unroll
      for (int j = 0; j < 4; j++) {
        int f = wc * 64 + j * 16 + lr;
        float bs = bias[f];
#pragma unroll
        for (int r = 0; r < 4; r++) {
          long R = R0 + wr * 64 + i * 16 + (lane >> 4) * 4 + r;
          int n = (int)(R & 63);
          out[R * 256 + f] = acc[i][j][r] * dscale[n * 256 + f] + bs;
        }
      }
    }
  } else {
    // transpose via LDS: Ts[f][row] then coalesced rows to h1ws[f][R0+ r]
    unsigned short* Ts = smem;   // [256][136]
#pragma unroll
    for (int i = 0; i < 4; i++) {
#pragma unroll
      for (int j = 0; j < 4; j++) {
        int fl = wc * 64 + j * 16 + lr;
        int rb = wr * 64 + i * 16 + (lane >> 4) * 4;
        u16x4 pk;
        pk[0] = f2bf(acc[i][j][0]); pk[1] = f2bf(acc[i][j][1]);
        pk[2] = f2bf(acc[i][j][2]); pk[3] = f2bf(acc[i][j][3]);
        *(u16x4*)(Ts + fl * 136 + rb) = pk;
      }
    }
    __syncthreads();
    unsigned short* h1ws = (unsigned short*)(ws_b + OFF_H1);
    int fl = tid >> 1, rb2 = (tid & 1) * 64;
    unsigned short* dst = h1ws + (long)fl * 131072 + R0 + rb2;
    const unsigned short* s = Ts + fl * 136 + rb2;
#pragma unroll
    for (int i = 0; i < 8; i++)
      *(u16x8*)(dst + i * 8) = *(const u16x8*)(s + i * 8);
  }
}

// ---------------------------------------------------------------- k_einsum
// grid (128, 16), block 256 (4 waves). Block tile: 16 b x 16 f, all 64 n.
// D'[b,n] = sum_m h1[f][b][m] * off[f][n][m]  (A = h1^T rows b, B = off^T)
__global__ __launch_bounds__(256) void k_einsum(char* __restrict__ ws_b,
                                                float* __restrict__ out) {
  const unsigned short* offp = (const unsigned short*)(ws_b + OFF_OFF);
  const unsigned short* h1ws = (const unsigned short*)(ws_b + OFF_H1);
  __shared__ __align__(16) unsigned short Ds[16 * 64 * 24];  // [b][n][24] 48KB
  const int tid = threadIdx.x;
  const long B0 = (long)blockIdx.x * 16;
  const int f0 = blockIdx.y * 16;
  const int wid = tid >> 6, lane = tid & 63;
  const int lr = lane & 15, lkb = (lane >> 4) * 8;

  for (int q = 0; q < 4; q++) {
    int fi = wid * 4 + q;            // 0..15
    long f = f0 + fi;
    f32x4 acc[4] = {};
    const unsigned short* ha = h1ws + f * 131072 + (B0 + lr) * 64;
    const unsigned short* ob = offp + f * 4096;
#pragma unroll
    for (int kt = 0; kt < 2; kt++) {
      fragA a = *(const fragA*)(ha + kt * 32 + lkb);
#pragma unroll
      for (int ct = 0; ct < 4; ct++) {
        fragA b = *(const fragA*)(ob + (ct * 16 + lr) * 64 + kt * 32 + lkb);
        acc[ct] = __builtin_amdgcn_mfma_f32_16x16x32_bf16(a, b, acc[ct], 0, 0, 0);
      }
    }
#pragma unroll
    for (int ct = 0; ct < 4; ct++) {
      int n = ct * 16 + lr;
#pragma unroll
      for (int r = 0; r < 4; r++) {
        int b = (lane >> 4) * 4 + r;
        Ds[(b * 64 + n) * 24 + fi] = f2bf(acc[ct][r]);
      }
    }
  }
  __syncthreads();
  // combine: RMW out rows; thread -> 4 (b,n) rows, 16 f each
#pragma unroll
  for (int i = 0; i < 4; i++) {
    int r = tid + 256 * i;                       // 0..1023 = b*64+n
    float* o = out + (B0 * 64 + r) * 256 + f0;
    const unsigned short* ds = Ds + r * 24;
    u16x8 d0 = *(const u16x8*)(ds);
    u16x8 d1 = *(const u16x8*)(ds + 8);
    float4 o0 = ((float4*)o)[0], o1 = ((float4*)o)[1];
    float4 o2 = ((float4*)o)[2], o3 = ((float4*)o)[3];
    o0.x += bf2f(d0[0]); o0.y += bf2f(d0[1]); o0.z += bf2f(d0[2]); o0.w += bf2f(d0[3]);
    o1.x += bf2f(d0[4]); o1.y += bf2f(d0[5]); o1.z += bf2f(d0[6]); o1.w += bf2f(d0[7]);
    o2.x += bf2f(d1[0]); o2.y += bf2f(d1[1]); o2.z += bf2f(d1[2]); o2.w += bf2f(d1[3]);
    o3.x += bf2f(d1[4]); o3.y += bf2f(d1[5]); o3.z += bf2f(d1[6]); o3.w += bf2f(d1[7]);
    ((float4*)o)[0] = o0; ((float4*)o)[1] = o1;
    ((float4*)o)[2] = o2; ((float4*)o)[3] = o3;
  }
}

// ---------------------------------------------------------------- launch
extern "C" void kernel_launch(void* const* d_in, const int* in_sizes, int n_in,
                              void* d_out, int out_size, void* d_ws, size_t ws_size,
                              hipStream_t stream) {
  const float* x    = (const float*)d_in[0];
  const float* W    = (const float*)d_in[1];
  const float* e    = (const float*)d_in[2];
  const float* bias = (const float*)d_in[3];
  const unsigned char* mask = (const unsigned char*)d_in[4];
  float* out = (float*)d_out;
  char* ws = (char*)d_ws;
  if (ws_size < (size_t)WS_NEED) return;   // defensive: avoid corrupting memory

  k_prep<<<4096, 256, 0, stream>>>(e, mask, ws);
  k_wt<<<32, 256, 0, stream>>>(W, ws);
  dim3 g2(2, 1024);
  k_gemm<<<g2, 512, 0, stream>>>(x, bias, ws, out);
  dim3 g3(128, 16);
  k_einsum<<<g3, 256, 0, stream>>>(ws, out);
}

// Round 2
// 205.507 us; speedup vs baseline: 1.1768x; 1.1768x over previous
//
#include <hip/hip_runtime.h>
#include <hip/hip_bf16.h>

// B=2048, N=64, C=256, F=256
// out[b,n,f] = d[f,n]*h0[b,n,f] + sum_m off[f,n,m]*h1[b,m,f] + bias[f]
// Fused design: one block = 8 batches x 32 f-channels. GEMM (h0,h1) with A
// streamed from global f32 x (cvt in VALU), B = W-slice in LDS; h1 lives only
// in LDS; einsum via per-f MFMA with off[f,n,m] read from L2; single out write.

typedef __attribute__((ext_vector_type(8))) short  fragA;   // 8 bf16 = 4 VGPR
typedef __attribute__((ext_vector_type(4))) float  f32x4;
typedef __attribute__((ext_vector_type(8))) unsigned short u16x8;
typedef __attribute__((ext_vector_type(4))) unsigned short u16x4;

// workspace layout (bytes)
constexpr long OFF_OFF = 0;                          // bf16 off [256][64][64] (2 MB)
constexpr long OFF_WT  = 2l * 1024 * 1024;           // bf16 Wt flat [512][256] (256 KB)
constexpr long OFF_DS  = OFF_WT + 512l * 256 * 2;    // f32 dscale [64][256]   (64 KB)
constexpr long WS_NEED = OFF_DS + 64l * 256 * 4;

static __device__ inline unsigned short f2bf(float f) {
  __hip_bfloat16 h = __float2bfloat16(f);
  return __builtin_bit_cast(unsigned short, h);
}
static __device__ inline float bf2f(unsigned short u) {
  unsigned int x = ((unsigned int)u) << 16;
  return __builtin_bit_cast(float, x);
}

// ---------------------------------------------------------------- k_prep
// one wave per (f,n) row of e; block = 4 rows. off [f][n][m] bf16, dscale [n][f] f32
__global__ __launch_bounds__(256) void k_prep(const float* __restrict__ e,
                                              const unsigned char* __restrict__ mask,
                                              char* __restrict__ ws_b) {
  unsigned short* off = (unsigned short*)(ws_b + OFF_OFF);
  float* dscale = (float*)(ws_b + OFF_DS);
  const int lane = threadIdx.x & 63;
  const int row  = blockIdx.x * 4 + (threadIdx.x >> 6);   // f*64 + n
  const int n = row & 63;

  // mask dtype sniff: diag is guaranteed true (self-loops).
  bool is_u8 = __all(mask[lane * 65] != 0);
  bool mv;
  if (is_u8) mv = mask[n * 64 + lane] != 0;
  else       mv = ((const int*)mask)[n * 64 + lane] != 0;

  float v = mv ? e[(long)row * 64 + lane] : -1e30f;
  float mx = v;
#pragma unroll
  for (int s = 32; s; s >>= 1) mx = fmaxf(mx, __shfl_xor(mx, s));
  float ex = mv ? __expf(v - mx) : 0.f;
  float sm = ex;
#pragma unroll
  for (int s = 32; s; s >>= 1) sm += __shfl_xor(sm, s);
  float adj = ex / sm;
  const int f = row >> 6;
  if (lane == n) dscale[n * 256 + f] = adj;
  off[(long)row * 64 + lane] = f2bf(lane == n ? 0.f : adj);
}

// ---------------------------------------------------------------- k_wt
// W[2][C][F] f32 -> Wt bf16 flat [512(j=w*256+f)][256(c)]
__global__ __launch_bounds__(256) void k_wt(const float* __restrict__ W,
                                            char* __restrict__ ws_b) {
  unsigned short* Wt = (unsigned short*)(ws_b + OFF_WT);
  __shared__ float t[64][65];
  const int bid = blockIdx.x;           // 32 blocks: w(2) x f0(4) x c0(4)
  const int w = bid >> 4, f0 = ((bid >> 2) & 3) * 64, c0 = (bid & 3) * 64;
  const int tr = threadIdx.x >> 2, tc = (threadIdx.x & 3) * 16;
  const float* src = W + ((long)(w * 256 + c0 + tr)) * 256 + f0 + tc;
#pragma unroll
  for (int i = 0; i < 16; i += 4) {
    float4 v = *(const float4*)(src + i);
    t[tr][tc + i] = v.x; t[tr][tc + i + 1] = v.y;
    t[tr][tc + i + 2] = v.z; t[tr][tc + i + 3] = v.w;
  }
  __syncthreads();
  u16x8 p0, p1;
#pragma unroll
  for (int i = 0; i < 8; i++)  p0[i] = f2bf(t[tc + i][tr]);
#pragma unroll
  for (int i = 0; i < 8; i++)  p1[i] = f2bf(t[tc + 8 + i][tr]);
  unsigned short* dst = Wt + ((long)(w * 256 + f0 + tr)) * 256 + c0 + tc;
  *(u16x8*)dst = p0;
  *(u16x8*)(dst + 8) = p1;
}

// ---------------------------------------------------------------- k_main
// grid 2048 linear, block 512 (8 waves). Block = 8 batches (512 rows) x 32 f.
// wave w owns batch w (rows Rw..Rw+63). GEMM cols 0..31 = h0(f0..f0+31),
// cols 32..63 = h1. Then h1 -> LDS, per-f einsum MFMA, fused epilogue.
__global__ __launch_bounds__(512, 4) void k_main(const float* __restrict__ x,
                                                 const float* __restrict__ bias,
                                                 const char* __restrict__ ws_b,
                                                 float* __restrict__ out) {
  const unsigned short* Wt   = (const unsigned short*)(ws_b + OFF_WT);
  const unsigned short* offp = (const unsigned short*)(ws_b + OFF_OFF);
  const float* dscale        = (const float*)(ws_b + OFF_DS);

  __shared__ __align__(16) unsigned short Bs[64 * 264];     // 33792 B
  __shared__ __align__(16) unsigned short Hb[19264];        // 38528 B (32 f x 584 + slack)

  const int tid = threadIdx.x;
  const int wid = tid >> 6, lane = tid & 63;
  const int lr = lane & 15, hi = lane >> 4;

  // XCD-aware remap: XCD k = wg%8 hosts bb in [k*32, k*32+32), fb cycles fast
  // -> off slice (2MB) stays hot per-XCD L2; x slices reused across 8 fb.
  const int wg = blockIdx.x;
  const int xcd = wg & 7, s = wg >> 3;           // s in 0..255
  const int bb = xcd * 32 + (s >> 3);            // 0..255 (8-batch groups)
  const int fb = s & 7;                          // 0..7
  const int f0 = fb * 32;
  const long R0 = (long)bb * 512;                // 512 rows per block
  const long Rw = R0 + wid * 64;                 // wave's 64 rows (1 batch)

  // ---- stage B tile: 64 "cols" (32 h0-f + 32 h1-f) x 256 K, pad 264
  {
    int c = tid >> 3, ch = (tid & 7) * 32;
    int wrow = (c < 32) ? (f0 + c) : (256 + f0 + c - 32);
    const unsigned short* src = Wt + (long)wrow * 256 + ch;
    unsigned short* d = &Bs[c * 264 + ch];
    *(u16x8*)(d)      = *(const u16x8*)(src);
    *(u16x8*)(d + 8)  = *(const u16x8*)(src + 8);
    *(u16x8*)(d + 16) = *(const u16x8*)(src + 16);
    *(u16x8*)(d + 24) = *(const u16x8*)(src + 24);
  }
  __syncthreads();

  // ---- GEMM: acc[i 0..3][j 0..3], rows Rw+i*16+lr, cols j*16+lr, K=256
  f32x4 acc[4][4] = {};
#pragma unroll
  for (int ks = 0; ks < 8; ks++) {
    fragA af[4], bfr[4];
#pragma unroll
    for (int i = 0; i < 4; i++) {
      const float* p = x + (Rw + i * 16 + lr) * 256 + ks * 32 + hi * 8;
      float4 v0 = *(const float4*)p;
      float4 v1 = *(const float4*)(p + 4);
      u16x8 t;
      t[0] = f2bf(v0.x); t[1] = f2bf(v0.y); t[2] = f2bf(v0.z); t[3] = f2bf(v0.w);
      t[4] = f2bf(v1.x); t[5] = f2bf(v1.y); t[6] = f2bf(v1.z); t[7] = f2bf(v1.w);
      af[i] = __builtin_bit_cast(fragA, t);
    }
#pragma unroll
    for (int j = 0; j < 4; j++)
      bfr[j] = *(const fragA*)&Bs[(j * 16 + lr) * 264 + ks * 32 + hi * 8];
#pragma unroll
    for (int i = 0; i < 4; i++)
#pragma unroll
      for (int j = 0; j < 4; j++)
        acc[i][j] = __builtin_amdgcn_mfma_f32_16x16x32_bf16(af[i], bfr[j], acc[i][j], 0, 0, 0);
  }

  // ---- h1 (j=2,3) -> LDS Hb[f_local][b=wid][m], per-f stride 584 shorts
#pragma unroll
  for (int i = 0; i < 4; i++) {
#pragma unroll
    for (int j = 2; j < 4; j++) {
      int fl = (j - 2) * 16 + lr;
      int m  = i * 16 + hi * 4;
      u16x4 pk;
      pk[0] = f2bf(acc[i][j][0]); pk[1] = f2bf(acc[i][j][1]);
      pk[2] = f2bf(acc[i][j][2]); pk[3] = f2bf(acc[i][j][3]);
      *(u16x4*)&Hb[fl * 584 + wid * 72 + m] = pk;
    }
  }
  __syncthreads();

  // ---- einsum: wave owns f_local = wid*4+q. C[b,n] = sum_m h1[b,m]*off[n,m].
  // A rows 8..15 are garbage (only 8 batches) -> C rows 8..15 discarded.
  // eins result overwritten in place into Hb[fl][b][n] (wave-private f slice).
#pragma unroll
  for (int q = 0; q < 4; q++) {
    int fl = wid * 4 + q;
    long fg = f0 + fl;
    f32x4 ea[4] = {};
    const unsigned short* ob = offp + fg * 4096;
#pragma unroll
    for (int kk = 0; kk < 2; kk++) {
      fragA a = *(const fragA*)&Hb[fl * 584 + lr * 72 + kk * 32 + hi * 8];
#pragma unroll
      for (int ct = 0; ct < 4; ct++) {
        fragA b = *(const fragA*)(ob + (ct * 16 + lr) * 64 + kk * 32 + hi * 8);
        ea[ct] = __builtin_amdgcn_mfma_f32_16x16x32_bf16(a, b, ea[ct], 0, 0, 0);
      }
    }
    if (hi < 2) {   // b = hi*4+r < 8 valid
#pragma unroll
      for (int ct = 0; ct < 4; ct++) {
#pragma unroll
        for (int r = 0; r < 4; r++) {
          int b = hi * 4 + r;
          int n = ct * 16 + lr;
          Hb[fl * 584 + b * 72 + n] = f2bf(ea[ct][r]);
        }
      }
    }
  }
  __syncthreads();

  // ---- epilogue: out = d[n,f]*h0 + eins + bias, single coalesced-ish write
#pragma unroll
  for (int i = 0; i < 4; i++) {
#pragma unroll
    for (int j = 0; j < 2; j++) {
      int fl = j * 16 + lr;
      int f  = f0 + fl;
      float bs = bias[f];
#pragma unroll
      for (int r = 0; r < 4; r++) {
        int m = i * 16 + hi * 4 + r;          // row within batch = n
        float ev = bf2f(Hb[fl * 584 + wid * 72 + m]);
        long R = Rw + m;
        out[R * 256 + f] = dscale[m * 256 + f] * acc[i][j][r] + ev + bs;
      }
    }
  }
}

// ---------------------------------------------------------------- launch
extern "C" void kernel_launch(void* const* d_in, const int* in_sizes, int n_in,
                              void* d_out, int out_size, void* d_ws, size_t ws_size,
                              hipStream_t stream) {
  const float* x    = (const float*)d_in[0];
  const float* W    = (const float*)d_in[1];
  const float* e    = (const float*)d_in[2];
  const float* bias = (const float*)d_in[3];
  const unsigned char* mask = (const unsigned char*)d_in[4];
  float* out = (float*)d_out;
  char* ws = (char*)d_ws;
  if (ws_size < (size_t)WS_NEED) return;

  k_prep<<<4096, 256, 0, stream>>>(e, mask, ws);
  k_wt<<<32, 256, 0, stream>>>(W, ws);
  k_main<<<2048, 512, 0, stream>>>(x, bias, ws, out);
}